// Round 1
// 603.114 us; speedup vs baseline: 1.1649x; 1.1649x over previous
//
#include <hip/hip_runtime.h>

#define B_ 8
#define C_ 64
#define N_ 512
#define T_ 288
#define K_ 32

typedef __bf16 bf16;
typedef __attribute__((ext_vector_type(4))) __bf16 bf16x4;
typedef __attribute__((ext_vector_type(8))) __bf16 bf16x8;
typedef __attribute__((ext_vector_type(4))) float f32x4;

// ---------------- K0: dtype-detect + convert HEs/EM to bf16 ----------------
// Every block re-derives the dtype flag from x[0..4096) read as bf16 (8 KB,
// L2-hot): if the buffer is really fp32, some |v| is astronomically large.
__global__ __launch_bounds__(256) void k_prep(const void* __restrict__ x,
                                              const void* __restrict__ hes,
                                              const void* __restrict__ em,
                                              bf16* __restrict__ hesb,
                                              bf16* __restrict__ hest,
                                              bf16* __restrict__ emb,
                                              int* __restrict__ flag) {
    __shared__ float sm[256];
    const bf16* xb = (const bf16*)x;
    float m = 0.f;
    for (int i = threadIdx.x; i < 4096; i += 256) {
        float a = fabsf((float)xb[i]);
        if (!(a <= 1000.f)) a = 1e30f;   // catches NaN too
        m = fmaxf(m, a);
    }
    sm[threadIdx.x] = m;
    __syncthreads();
    for (int s = 128; s > 0; s >>= 1) {
        if (threadIdx.x < s) sm[threadIdx.x] = fmaxf(sm[threadIdx.x], sm[threadIdx.x + s]);
        __syncthreads();
    }
    const int f32 = (sm[0] > 1000.f) ? 1 : 0;   // 1 = fp32 buffers
    if (blockIdx.x == 0 && threadIdx.x == 0) *flag = f32;

    int idx = blockIdx.x * 256 + threadIdx.x;
    if (idx < N_ * K_) {
        float v = f32 ? ((const float*)hes)[idx] : (float)((const bf16*)hes)[idx];
        hesb[idx] = (bf16)v;
        int n = idx >> 5, k = idx & 31;
        hest[k * N_ + n] = (bf16)v;
    }
    if (idx < K_ * K_) {
        float v = f32 ? ((const float*)em)[idx] : (float)((const bf16*)em)[idx];
        emb[idx] = (bf16)v;
    }
}

// ---------------- K1: HF = HEs^T @ X_c ; HO = relu(EM@HF)+HF -------------
// grid (9 t-tiles, C, B), block 64 (1 wave). X is staged per 128n x 32t chunk
// with coalesced float4 loads (8 rows x 128 B = 1 KB/instr) into a transposed
// bf16 LDS tile xT[t][n] (stride 136 -> 16B-aligned rows, conflict-free
// ds_read_b128 fragment reads). Replaces 256 scalar gathers/lane.
template <int F32>
__device__ __forceinline__ void hyper_body(const void* __restrict__ x,
                                           const bf16* __restrict__ hest,
                                           const bf16* __restrict__ emb,
                                           bf16* __restrict__ ho) {
    const int tile = blockIdx.x, c = blockIdx.y, b = blockIdx.z;
    const int lane = threadIdx.x;
    const int col  = lane & 15;   // m/col within 16x16 tiles
    const int q    = lane >> 4;   // quad
    const int t0   = tile * 32;
    const size_t xbase = ((size_t)(b * C_ + c)) * N_ * T_;

    __shared__ bf16  xT[32][136];   // [t][n-within-chunk], pad->16B-aligned rows
    __shared__ float hf[K_][33];

    const int tq = lane & 7;        // t-quad for staging (4 t's)
    const int rw = lane >> 3;       // row-within-8 for staging

    f32x4 acc[2][2] = {};
    for (int chunk = 0; chunk < 4; ++chunk) {
        const int nc = chunk * 128;
        // ---- stage 128n x 32t, transposed ----
        #pragma unroll
        for (int it = 0; it < 16; ++it) {
            const int row = it * 8 + rw;   // 0..127
            const size_t gi = xbase + (size_t)(nc + row) * T_ + t0 + 4 * tq;
            float v0, v1, v2, v3;
            if (F32) {
                f32x4 v = *(const f32x4*)((const float*)x + gi);
                v0 = v[0]; v1 = v[1]; v2 = v[2]; v3 = v[3];
            } else {
                bf16x4 v = *(const bf16x4*)((const bf16*)x + gi);
                v0 = (float)v[0]; v1 = (float)v[1]; v2 = (float)v[2]; v3 = (float)v[3];
            }
            xT[4 * tq + 0][row] = (bf16)v0;
            xT[4 * tq + 1][row] = (bf16)v1;
            xT[4 * tq + 2][row] = (bf16)v2;
            xT[4 * tq + 3][row] = (bf16)v3;
        }
        __syncthreads();   // 1 wave: cheap; orders stage->read
        // ---- 4 K-steps of 32 over this chunk ----
        #pragma unroll
        for (int s = 0; s < 4; ++s) {
            const int nl = s * 32;
            const int ng = nc + nl;
            bf16x8 a0 = *(const bf16x8*)(hest + (size_t)(col) * N_ + ng + 8 * q);
            bf16x8 a1 = *(const bf16x8*)(hest + (size_t)(16 + col) * N_ + ng + 8 * q);
            bf16x8 b0 = *(const bf16x8*)(&xT[col][nl + 8 * q]);
            bf16x8 b1 = *(const bf16x8*)(&xT[16 + col][nl + 8 * q]);
            acc[0][0] = __builtin_amdgcn_mfma_f32_16x16x32_bf16(a0, b0, acc[0][0], 0, 0, 0);
            acc[0][1] = __builtin_amdgcn_mfma_f32_16x16x32_bf16(a0, b1, acc[0][1], 0, 0, 0);
            acc[1][0] = __builtin_amdgcn_mfma_f32_16x16x32_bf16(a1, b0, acc[1][0], 0, 0, 0);
            acc[1][1] = __builtin_amdgcn_mfma_f32_16x16x32_bf16(a1, b1, acc[1][1], 0, 0, 0);
        }
        __syncthreads();   // WAR: next chunk overwrites xT
    }

    // Stage HF to LDS (C/D layout: row=4q+r, col=col within each 16x16 tile)
    #pragma unroll
    for (int mt = 0; mt < 2; ++mt)
        #pragma unroll
        for (int tt = 0; tt < 2; ++tt)
            #pragma unroll
            for (int r = 0; r < 4; ++r)
                hf[16 * mt + 4 * q + r][16 * tt + col] = acc[mt][tt][r];
    __syncthreads();

    // HM = EM @ HF: one K=32 MFMA per (mt, tt)
    f32x4 acc2[2][2];
    #pragma unroll
    for (int mt = 0; mt < 2; ++mt) {
        bf16x8 a = *(const bf16x8*)(emb + (size_t)(16 * mt + col) * K_ + 8 * q);
        #pragma unroll
        for (int tt = 0; tt < 2; ++tt) {
            bf16x8 bb;
            #pragma unroll
            for (int jj = 0; jj < 8; ++jj)
                bb[jj] = (bf16)hf[8 * q + jj][16 * tt + col];
            f32x4 zero = {};
            acc2[mt][tt] = __builtin_amdgcn_mfma_f32_16x16x32_bf16(a, bb, zero, 0, 0, 0);
        }
    }

    // HO = relu(HM) + HF, store bf16 as [b][c][t][k] (k innermost)
    #pragma unroll
    for (int mt = 0; mt < 2; ++mt)
        #pragma unroll
        for (int tt = 0; tt < 2; ++tt) {
            bf16x4 v;
            #pragma unroll
            for (int r = 0; r < 4; ++r) {
                float hv = acc2[mt][tt][r];
                hv = hv > 0.f ? hv : 0.f;
                hv += acc[mt][tt][r];
                v[r] = (bf16)hv;   // k = 16*mt + 4*q + r
            }
            *(bf16x4*)(ho + (((size_t)(b * C_ + c)) * T_ + t0 + 16 * tt + col) * K_
                          + 16 * mt + 4 * q) = v;
        }
}

__global__ __launch_bounds__(64, 3) void k_hyper(const void* __restrict__ x,
                                                 const int* __restrict__ flag,
                                                 const bf16* __restrict__ hest,
                                                 const bf16* __restrict__ emb,
                                                 bf16* __restrict__ ho) {
    if (*flag) hyper_body<1>(x, hest, emb, ho);
    else       hyper_body<0>(x, hest, emb, ho);
}

// ---------------- K2: y = relu(HEs @ HO); z = y + x; LN over C; store ----
// 2304 blocks x 512 thr (8 waves = 4 c-groups x 2 t-halves), t-tile 32.
// Operand-swapped MFMA: D = mfma(HO^T-frag, HEs-frag) -> D row = t, so each
// lane's 4 acc regs are 4 consecutive t -> float4 residual loads + stores.
// Block decode is XCD-chunked: each XCD owns one batch b (ho slice 1.2 MB
// stays L2-resident across its 288 blocks).
template <int F32>
__device__ __forceinline__ void scatter_body(const void* __restrict__ x,
                                             const bf16* __restrict__ hesb,
                                             const bf16* __restrict__ ho,
                                             void* __restrict__ outp) {
    const int wg  = blockIdx.x;
    const int b   = wg & 7;           // XCD-chunked: 2304 = 8 * 288
    const int pos = wg >> 3;          // 0..287
    const int bx  = pos % 9;          // t-tile of 32
    const int n0  = (pos / 9) * 16;   // n-tile of 16

    const int tid   = threadIdx.x;
    const int w     = tid >> 6;
    const int lane  = tid & 63;
    const int col   = lane & 15;      // n within tile
    const int q     = lane >> 4;      // t-quad
    const int thalf = w & 1;
    const int cgrp  = w >> 1;
    const int t0    = bx * 32 + thalf * 16;

    // B-frag: B[k=8q+j][col=n] = HEs[n0+col][8q+j] (contiguous 16B)
    bf16x8 hb = *(const bf16x8*)(hesb + (size_t)(n0 + col) * K_ + 8 * q);

    f32x4 z[16];
    float s1[4] = {0.f, 0.f, 0.f, 0.f}, s2[4] = {0.f, 0.f, 0.f, 0.f};
    const bf16* hob = ho + (((size_t)(b * C_)) * T_ + t0 + col) * K_ + 8 * q;
    const size_t xb = ((size_t)b * C_) * (size_t)N_ * T_;
    #pragma unroll
    for (int i = 0; i < 16; ++i) {
        const int c = cgrp * 16 + i;
        // A-frag: A[row=t-col][k=8q+j] = HO[b][c][t0+col][8q+j] (contiguous 16B)
        bf16x8 a = *(const bf16x8*)(hob + (size_t)c * T_ * K_);
        f32x4 zero = {};
        f32x4 zz = __builtin_amdgcn_mfma_f32_16x16x32_bf16(a, hb, zero, 0, 0, 0);
        // D[row=4q+r][col]: row ~ t = t0+4q+r, col ~ n = n0+col
        const size_t xi = xb + ((size_t)c * N_ + n0 + col) * T_ + t0 + 4 * q;
        f32x4 xv;
        if (F32) {
            xv = *(const f32x4*)((const float*)x + xi);
        } else {
            bf16x4 x4 = *(const bf16x4*)((const bf16*)x + xi);
            xv[0] = (float)x4[0]; xv[1] = (float)x4[1];
            xv[2] = (float)x4[2]; xv[3] = (float)x4[3];
        }
        #pragma unroll
        for (int r = 0; r < 4; ++r) {
            float v = zz[r];
            v = v > 0.f ? v : 0.f;
            v += xv[r];
            zz[r] = v;
            s1[r] += v;
            s2[r] += v * v;
        }
        z[i] = zz;
    }

    __shared__ float sh1[2][4][16][17];
    __shared__ float sh2[2][4][16][17];
    #pragma unroll
    for (int r = 0; r < 4; ++r) {
        sh1[thalf][cgrp][4 * q + r][col] = s1[r];
        sh2[thalf][cgrp][4 * q + r][col] = s2[r];
    }
    __syncthreads();

    {   // one thread per (t-half, t-row, n-col): reduce across 4 c-groups
        const int th = tid >> 8, rr = (tid >> 4) & 15, cc = tid & 15;
        float S1 = sh1[th][0][rr][cc] + sh1[th][1][rr][cc]
                 + sh1[th][2][rr][cc] + sh1[th][3][rr][cc];
        float S2 = sh2[th][0][rr][cc] + sh2[th][1][rr][cc]
                 + sh2[th][2][rr][cc] + sh2[th][3][rr][cc];
        float mu  = S1 * (1.f / 64.f);
        float var = S2 * (1.f / 64.f) - mu * mu;
        float rs  = rsqrtf(var + 1e-5f);
        sh1[th][0][rr][cc] = mu;   // own slot: no cross-thread read of it
        sh2[th][0][rr][cc] = rs;
    }
    __syncthreads();

    float mu_r[4], rs_r[4];
    #pragma unroll
    for (int r = 0; r < 4; ++r) {
        mu_r[r] = sh1[thalf][0][4 * q + r][col];
        rs_r[r] = sh2[thalf][0][4 * q + r][col];
    }
    #pragma unroll
    for (int i = 0; i < 16; ++i) {
        const int c = cgrp * 16 + i;
        const size_t oi = ((size_t)(b * C_ + c) * N_ + n0 + col) * T_ + t0 + 4 * q;
        if (F32) {
            f32x4 v;
            #pragma unroll
            for (int r = 0; r < 4; ++r) v[r] = (z[i][r] - mu_r[r]) * rs_r[r];
            *(f32x4*)((float*)outp + oi) = v;
        } else {
            bf16x4 v;
            #pragma unroll
            for (int r = 0; r < 4; ++r) v[r] = (bf16)((z[i][r] - mu_r[r]) * rs_r[r]);
            *(bf16x4*)((bf16*)outp + oi) = v;
        }
    }
}

__global__ __launch_bounds__(512, 2) void k_scatter_ln(const void* __restrict__ x,
                                                       const int* __restrict__ flag,
                                                       const bf16* __restrict__ hesb,
                                                       const bf16* __restrict__ ho,
                                                       void* __restrict__ outp) {
    if (*flag) scatter_body<1>(x, hesb, ho, outp);
    else       scatter_body<0>(x, hesb, ho, outp);
}

extern "C" void kernel_launch(void* const* d_in, const int* in_sizes, int n_in,
                              void* d_out, int out_size, void* d_ws, size_t ws_size,
                              hipStream_t stream) {
    const void* x   = d_in[0];
    const void* hes = d_in[1];
    const void* em  = d_in[2];

    char* ws = (char*)d_ws;
    int*  flag = (int*)ws;                        // 4 B (+pad)
    bf16* hesb = (bf16*)(ws + 64);                // 32 KB  [N][K]
    bf16* hest = hesb + (size_t)N_ * K_;          // 32 KB  [K][N]
    bf16* emb  = hest + (size_t)K_ * N_;          // 2 KB   [K][K]
    bf16* ho   = emb  + (size_t)K_ * K_;          // 9.44 MB [B][C][T][K]

    k_prep<<<dim3((N_ * K_ + 255) / 256), 256, 0, stream>>>(x, hes, em, hesb, hest, emb, flag);
    k_hyper<<<dim3(T_ / 32, C_, B_), 64, 0, stream>>>(x, flag, hest, emb, ho);
    k_scatter_ln<<<dim3((T_ / 32) * (N_ / 16) * B_, 1, 1), 512, 0, stream>>>(x, flag, hesb, ho, d_out);
}